// Round 1
// baseline (394.759 us; speedup 1.0000x reference)
//
#include <hip/hip_runtime.h>

typedef __attribute__((ext_vector_type(8))) __bf16 bf16x8;
typedef __attribute__((ext_vector_type(4))) float f32x4;

#define T_SEQ 2048
#define NH 16
#define HD 64
#define CDIM 1024
#define MTOT 4096  // B*T

// ---------------- convert fp32 -> bf16 ----------------
__global__ __launch_bounds__(256) void cvt_bf16_kernel(const float* __restrict__ in,
                                                       __bf16* __restrict__ out, int n) {
    int i = (blockIdx.x * 256 + threadIdx.x) * 8;
    if (i + 8 <= n) {
        float4 f0 = *(const float4*)(in + i);
        float4 f1 = *(const float4*)(in + i + 4);
        bf16x8 o;
        o[0] = (__bf16)f0.x; o[1] = (__bf16)f0.y; o[2] = (__bf16)f0.z; o[3] = (__bf16)f0.w;
        o[4] = (__bf16)f1.x; o[5] = (__bf16)f1.y; o[6] = (__bf16)f1.z; o[7] = (__bf16)f1.w;
        *(bf16x8*)(out + i) = o;
    }
}

// ---------------- transpose fp32 [R][C] -> bf16 [C][R] ----------------
__global__ __launch_bounds__(256) void transpose_bf16_kernel(const float* __restrict__ in,
                                                             __bf16* __restrict__ out,
                                                             int R, int C) {
    __shared__ float tile[32][33];
    int c0 = blockIdx.x * 32, r0 = blockIdx.y * 32;
    int tx = threadIdx.x, ty = threadIdx.y;
#pragma unroll
    for (int i = 0; i < 4; i++)
        tile[ty + i * 8][tx] = in[(size_t)(r0 + ty + i * 8) * C + c0 + tx];
    __syncthreads();
#pragma unroll
    for (int i = 0; i < 4; i++)
        out[(size_t)(c0 + ty + i * 8) * R + r0 + tx] = (__bf16)tile[tx][ty + i * 8];
}

// ---------------- GEMM: C[m][n] = sum_k A[m][k]*Bt[n][k] + bias[n] ----------------
// mode 0: scatter bf16 into Q/K/V per-head layout [b][h][t][64]
// mode 1: fp32 store to outf [M][N]
__global__ __launch_bounds__(256) void gemm_bt_kernel(
    const __bf16* __restrict__ A, const __bf16* __restrict__ Bt,
    const float* __restrict__ bias, int M, int N, int K, int mode,
    __bf16* __restrict__ Qb, __bf16* __restrict__ Kb, __bf16* __restrict__ Vb,
    float* __restrict__ outf)
{
    __shared__ __bf16 As[128][72];
    __shared__ __bf16 Bs[128][72];

    int tid = threadIdx.x;
    int lane = tid & 63, wid = tid >> 6;
    int quad = lane >> 4, r16 = lane & 15;
    int wm = (wid >> 1) * 64, wn = (wid & 1) * 64;
    int bm = blockIdx.y * 128, bn = blockIdx.x * 128;

    f32x4 zero4 = {0.f, 0.f, 0.f, 0.f};
    f32x4 acc[4][4];
#pragma unroll
    for (int mi = 0; mi < 4; mi++)
#pragma unroll
        for (int ni = 0; ni < 4; ni++) acc[mi][ni] = zero4;

    int arow = tid >> 1, acol = (tid & 1) * 32;
    const __bf16* Ag = A + (size_t)(bm + arow) * K + acol;
    const __bf16* Bg = Bt + (size_t)(bn + arow) * K + acol;

    for (int kt = 0; kt < K; kt += 64) {
        uint4 av[4], bv[4];
#pragma unroll
        for (int i = 0; i < 4; i++) {
            av[i] = *(const uint4*)(Ag + kt + i * 8);
            bv[i] = *(const uint4*)(Bg + kt + i * 8);
        }
        __syncthreads();  // previous iteration's frag reads done
#pragma unroll
        for (int i = 0; i < 4; i++) {
            *(uint4*)&As[arow][acol + i * 8] = av[i];
            *(uint4*)&Bs[arow][acol + i * 8] = bv[i];
        }
        __syncthreads();
#pragma unroll
        for (int ks = 0; ks < 2; ks++) {
            bf16x8 af[4], bfr[4];
#pragma unroll
            for (int i = 0; i < 4; i++) {
                af[i] = *(const bf16x8*)&As[wm + i * 16 + r16][ks * 32 + quad * 8];
                bfr[i] = *(const bf16x8*)&Bs[wn + i * 16 + r16][ks * 32 + quad * 8];
            }
#pragma unroll
            for (int mi = 0; mi < 4; mi++)
#pragma unroll
                for (int ni = 0; ni < 4; ni++)
                    acc[mi][ni] = __builtin_amdgcn_mfma_f32_16x16x32_bf16(
                        af[mi], bfr[ni], acc[mi][ni], 0, 0, 0);
        }
    }

    // epilogue
#pragma unroll
    for (int mi = 0; mi < 4; mi++) {
#pragma unroll
        for (int ni = 0; ni < 4; ni++) {
            int col = bn + wn + ni * 16 + r16;
            float bv = bias[col];
#pragma unroll
            for (int rg = 0; rg < 4; rg++) {
                int row = bm + wm + mi * 16 + quad * 4 + rg;
                float val = acc[mi][ni][rg] + bv;
                if (mode == 0) {
                    int sel = col >> 10;   // 0:q 1:k 2:v
                    int c = col & 1023;
                    int h = c >> 6, d = c & 63;
                    int b = row >> 11, t = row & 2047;
                    size_t idx = ((size_t)((b * NH + h) * T_SEQ + t)) * HD + d;
                    __bf16 v = (__bf16)val;
                    if (sel == 0) Qb[idx] = v;
                    else if (sel == 1) Kb[idx] = v;
                    else Vb[idx] = v;
                } else {
                    outf[(size_t)row * N + col] = val;
                }
            }
        }
    }
}

// ---------------- flash attention: per (b,h) 128 q-rows per block ----------------
__global__ __launch_bounds__(256) void attn_kernel(
    const __bf16* __restrict__ Qb, const __bf16* __restrict__ Kb,
    const __bf16* __restrict__ Vb, __bf16* __restrict__ y1)
{
    __shared__ __bf16 Ks[64][72];
    __shared__ __bf16 Vt[64][72];
    __shared__ __bf16 Ps[4][32][72];

    int tid = threadIdx.x;
    int lane = tid & 63, w = tid >> 6;
    int quad = lane >> 4, r16 = lane & 15;
    int bh = blockIdx.y;
    int qb = blockIdx.x * 128;
    const __bf16* Qh = Qb + (size_t)bh * T_SEQ * HD;
    const __bf16* Kh = Kb + (size_t)bh * T_SEQ * HD;
    const __bf16* Vh = Vb + (size_t)bh * T_SEQ * HD;

    const float NEG_INF = -__builtin_inff();
    const float scale = 0.125f;  // 1/sqrt(64)

    // Q fragments (A-operand), loaded once
    bf16x8 qf[2][2];
#pragma unroll
    for (int mi = 0; mi < 2; mi++)
#pragma unroll
        for (int ks = 0; ks < 2; ks++)
            qf[mi][ks] = *(const bf16x8*)(Qh + (size_t)(qb + w * 32 + mi * 16 + r16) * HD +
                                          ks * 32 + quad * 8);

    f32x4 zero4 = {0.f, 0.f, 0.f, 0.f};
    f32x4 o[2][4];
    float m_i[2][4], l_i[2][4];
#pragma unroll
    for (int mi = 0; mi < 2; mi++) {
#pragma unroll
        for (int nd = 0; nd < 4; nd++) o[mi][nd] = zero4;
#pragma unroll
        for (int rg = 0; rg < 4; rg++) { m_i[mi][rg] = NEG_INF; l_i[mi][rg] = 0.f; }
    }

    int w0 = qb + w * 32;        // wave's first row
    int row_hi = w0 + 31;        // wave's last row
    int nkt = qb / 64 + 2;
    if (nkt > T_SEQ / 64) nkt = T_SEQ / 64;

    int srow = tid >> 2, sseg = tid & 3;

    for (int kt = 0; kt < nkt; kt++) {
        int kb = kt * 64;
        const __bf16* kp = Kh + (size_t)(kb + srow) * HD + sseg * 16;
        const __bf16* vp = Vh + (size_t)(kb + srow) * HD + sseg * 16;
        bf16x8 kv0 = *(const bf16x8*)kp;
        bf16x8 kv1 = *(const bf16x8*)(kp + 8);
        bf16x8 vv0 = *(const bf16x8*)vp;
        bf16x8 vv1 = *(const bf16x8*)(vp + 8);
        __syncthreads();  // prior iter's LDS reads done
        *(bf16x8*)&Ks[srow][sseg * 16] = kv0;
        *(bf16x8*)&Ks[srow][sseg * 16 + 8] = kv1;
#pragma unroll
        for (int j = 0; j < 8; j++) {
            Vt[sseg * 16 + j][srow] = vv0[j];
            Vt[sseg * 16 + 8 + j][srow] = vv1[j];
        }
        __syncthreads();

        if (kb <= row_hi) {  // wave-uniform
            // S = Q*K^T
            f32x4 s[2][4];
#pragma unroll
            for (int mi = 0; mi < 2; mi++)
#pragma unroll
                for (int ni = 0; ni < 4; ni++) s[mi][ni] = zero4;
#pragma unroll
            for (int ks = 0; ks < 2; ks++) {
                bf16x8 kf[4];
#pragma unroll
                for (int ni = 0; ni < 4; ni++)
                    kf[ni] = *(const bf16x8*)&Ks[ni * 16 + r16][ks * 32 + quad * 8];
#pragma unroll
                for (int mi = 0; mi < 2; mi++)
#pragma unroll
                    for (int ni = 0; ni < 4; ni++)
                        s[mi][ni] = __builtin_amdgcn_mfma_f32_16x16x32_bf16(
                            qf[mi][ks], kf[ni], s[mi][ni], 0, 0, 0);
            }
            // scale + causal mask
            bool diag = (kb + 63 > w0);
#pragma unroll
            for (int mi = 0; mi < 2; mi++)
#pragma unroll
                for (int ni = 0; ni < 4; ni++)
#pragma unroll
                    for (int rg = 0; rg < 4; rg++) {
                        float v = s[mi][ni][rg] * scale;
                        if (diag) {
                            int rrow = w0 + mi * 16 + quad * 4 + rg;
                            int ccol = kb + ni * 16 + r16;
                            if (ccol > rrow) v = NEG_INF;
                        }
                        s[mi][ni][rg] = v;
                    }
            // online softmax per row
#pragma unroll
            for (int mi = 0; mi < 2; mi++) {
#pragma unroll
                for (int rg = 0; rg < 4; rg++) {
                    float mx = fmaxf(fmaxf(s[mi][0][rg], s[mi][1][rg]),
                                     fmaxf(s[mi][2][rg], s[mi][3][rg]));
#pragma unroll
                    for (int off = 1; off < 16; off <<= 1)
                        mx = fmaxf(mx, __shfl_xor(mx, off, 64));
                    float mnew = fmaxf(m_i[mi][rg], mx);
                    float alpha = __expf(m_i[mi][rg] - mnew);
                    float rs = 0.f;
#pragma unroll
                    for (int ni = 0; ni < 4; ni++) {
                        float p = __expf(s[mi][ni][rg] - mnew);
                        s[mi][ni][rg] = p;
                        rs += p;
                    }
#pragma unroll
                    for (int off = 1; off < 16; off <<= 1)
                        rs += __shfl_xor(rs, off, 64);
                    l_i[mi][rg] = l_i[mi][rg] * alpha + rs;
                    m_i[mi][rg] = mnew;
#pragma unroll
                    for (int nd = 0; nd < 4; nd++) o[mi][nd][rg] *= alpha;
                }
            }
            // P -> LDS (bf16), per-wave private region
#pragma unroll
            for (int mi = 0; mi < 2; mi++)
#pragma unroll
                for (int ni = 0; ni < 4; ni++)
#pragma unroll
                    for (int rg = 0; rg < 4; rg++)
                        Ps[w][mi * 16 + quad * 4 + rg][ni * 16 + r16] =
                            (__bf16)s[mi][ni][rg];
            // PV
#pragma unroll
            for (int ks = 0; ks < 2; ks++) {
                bf16x8 pf[2], vf[4];
#pragma unroll
                for (int mi = 0; mi < 2; mi++)
                    pf[mi] = *(const bf16x8*)&Ps[w][mi * 16 + r16][ks * 32 + quad * 8];
#pragma unroll
                for (int nd = 0; nd < 4; nd++)
                    vf[nd] = *(const bf16x8*)&Vt[nd * 16 + r16][ks * 32 + quad * 8];
#pragma unroll
                for (int mi = 0; mi < 2; mi++)
#pragma unroll
                    for (int nd = 0; nd < 4; nd++)
                        o[mi][nd] = __builtin_amdgcn_mfma_f32_16x16x32_bf16(
                            pf[mi], vf[nd], o[mi][nd], 0, 0, 0);
            }
        }
    }

    // epilogue: y1[b*T+t][h*64+d] = o / l
    int b = bh >> 4, h = bh & 15;
#pragma unroll
    for (int mi = 0; mi < 2; mi++) {
#pragma unroll
        for (int rg = 0; rg < 4; rg++) {
            float inv = 1.f / l_i[mi][rg];
            int t = qb + w * 32 + mi * 16 + quad * 4 + rg;
#pragma unroll
            for (int nd = 0; nd < 4; nd++) {
                float val = o[mi][nd][rg] * inv;
                y1[(size_t)(b * T_SEQ + t) * CDIM + h * HD + nd * 16 + r16] = (__bf16)val;
            }
        }
    }
}

extern "C" void kernel_launch(void* const* d_in, const int* in_sizes, int n_in,
                              void* d_out, int out_size, void* d_ws, size_t ws_size,
                              hipStream_t stream) {
    const float* x = (const float*)d_in[0];
    const float* W_attn = (const float*)d_in[1];
    const float* b_attn = (const float*)d_in[2];
    const float* W_proj = (const float*)d_in[3];
    const float* b_proj = (const float*)d_in[4];
    float* out = (float*)d_out;

    char* p = (char*)d_ws;
    __bf16* xb = (__bf16*)p;   p += (size_t)MTOT * CDIM * 2;       // 8 MB (reused as y1)
    __bf16* WaT = (__bf16*)p;  p += (size_t)3 * CDIM * CDIM * 2;   // 6 MB
    __bf16* WpT = (__bf16*)p;  p += (size_t)CDIM * CDIM * 2;       // 2 MB
    __bf16* Qb = (__bf16*)p;   p += (size_t)MTOT * CDIM * 2;       // 8 MB
    __bf16* Kb = (__bf16*)p;   p += (size_t)MTOT * CDIM * 2;       // 8 MB
    __bf16* Vb = (__bf16*)p;   p += (size_t)MTOT * CDIM * 2;       // 8 MB
    __bf16* y1 = xb;  // x no longer needed after QKV GEMM

    cvt_bf16_kernel<<<2048, 256, 0, stream>>>(x, xb, MTOT * CDIM);
    transpose_bf16_kernel<<<dim3(96, 32), dim3(32, 8), 0, stream>>>(W_attn, WaT, CDIM, 3 * CDIM);
    transpose_bf16_kernel<<<dim3(32, 32), dim3(32, 8), 0, stream>>>(W_proj, WpT, CDIM, CDIM);
    gemm_bt_kernel<<<dim3(24, 32), 256, 0, stream>>>(xb, WaT, b_attn, MTOT, 3 * CDIM, CDIM, 0,
                                                     Qb, Kb, Vb, nullptr);
    attn_kernel<<<dim3(16, 32), 256, 0, stream>>>(Qb, Kb, Vb, y1);
    gemm_bt_kernel<<<dim3(8, 32), 256, 0, stream>>>(y1, WpT, b_proj, MTOT, CDIM, CDIM, 1,
                                                    nullptr, nullptr, nullptr, out);
}

// Round 2
// 319.289 us; speedup vs baseline: 1.2364x; 1.2364x over previous
//
#include <hip/hip_runtime.h>

typedef __attribute__((ext_vector_type(8))) __bf16 bf16x8;
typedef __attribute__((ext_vector_type(4))) float f32x4;

#define T_SEQ 2048
#define NH 16
#define HD 64
#define CDIM 1024
#define NQKV 3072
#define MTOT 4096  // B*T

__device__ __forceinline__ void async_load16(const void* g, void* l) {
    __builtin_amdgcn_global_load_lds(
        (const __attribute__((address_space(1))) void*)g,
        (__attribute__((address_space(3))) void*)l, 16, 0, 0);
}

// ---------------- convert fp32 -> bf16 ----------------
__global__ __launch_bounds__(256) void cvt_bf16_kernel(const float* __restrict__ in,
                                                       __bf16* __restrict__ out, int n) {
    int i = (blockIdx.x * 256 + threadIdx.x) * 8;
    if (i + 8 <= n) {
        float4 f0 = *(const float4*)(in + i);
        float4 f1 = *(const float4*)(in + i + 4);
        bf16x8 o;
        o[0] = (__bf16)f0.x; o[1] = (__bf16)f0.y; o[2] = (__bf16)f0.z; o[3] = (__bf16)f0.w;
        o[4] = (__bf16)f1.x; o[5] = (__bf16)f1.y; o[6] = (__bf16)f1.z; o[7] = (__bf16)f1.w;
        *(bf16x8*)(out + i) = o;
    }
}

// ---------------- transpose fp32 [R][C] -> bf16 [C][R] ----------------
__global__ __launch_bounds__(256) void transpose_bf16_kernel(const float* __restrict__ in,
                                                             __bf16* __restrict__ out,
                                                             int R, int C) {
    __shared__ float tile[32][33];
    int c0 = blockIdx.x * 32, r0 = blockIdx.y * 32;
    int tx = threadIdx.x, ty = threadIdx.y;
#pragma unroll
    for (int i = 0; i < 4; i++)
        tile[ty + i * 8][tx] = in[(size_t)(r0 + ty + i * 8) * C + c0 + tx];
    __syncthreads();
#pragma unroll
    for (int i = 0; i < 4; i++)
        out[(size_t)(c0 + ty + i * 8) * R + r0 + tx] = (__bf16)tile[tx][ty + i * 8];
}

// ---------------- GEMM: C[m][n] = sum_k A[m][k]*Bt[n][k] + bias[n] ----------------
// mode 0: bf16 store to outb [M][N];  mode 1: fp32 store to outf [M][N]
__global__ __launch_bounds__(256) void gemm_bt_kernel(
    const __bf16* __restrict__ A, const __bf16* __restrict__ Bt,
    const float* __restrict__ bias, int M, int N, int K, int mode,
    __bf16* __restrict__ outb, float* __restrict__ outf)
{
    __shared__ __bf16 As[128 * 64];   // unpadded: global_load_lds layout
    __shared__ __bf16 Bs[128 * 64];

    int tid = threadIdx.x;
    int lane = tid & 63, wid = tid >> 6;
    int quad = lane >> 4, r16 = lane & 15;
    int wm = (wid >> 1) * 64, wn = (wid & 1) * 64;
    int bm = blockIdx.y * 128, bn = blockIdx.x * 128;

    f32x4 acc[4][4] = {};

    // staging: wave wid covers tile rows [wid*32, wid*32+32)
    int lrow = lane >> 3;          // 0..7
    int lcol = (lane & 7) * 8;     // element col within 64
    const __bf16* Ag = A + (size_t)(bm + wid * 32 + lrow) * K + lcol;
    const __bf16* Bg = Bt + (size_t)(bn + wid * 32 + lrow) * K + lcol;
    char* lA = (char*)As + wid * 4096;
    char* lB = (char*)Bs + wid * 4096;

    for (int kt = 0; kt < K; kt += 64) {
        __syncthreads();  // previous iteration's frag reads done
#pragma unroll
        for (int i = 0; i < 4; i++) {
            async_load16(Ag + kt + (size_t)i * 8 * K, lA + i * 1024);
            async_load16(Bg + kt + (size_t)i * 8 * K, lB + i * 1024);
        }
        __syncthreads();  // vmcnt drain + barrier
#pragma unroll
        for (int ks = 0; ks < 2; ks++) {
            bf16x8 af[4], bfr[4];
#pragma unroll
            for (int i = 0; i < 4; i++) {
                af[i] = *(const bf16x8*)&As[(wm + i * 16 + r16) * 64 + ks * 32 + quad * 8];
                bfr[i] = *(const bf16x8*)&Bs[(wn + i * 16 + r16) * 64 + ks * 32 + quad * 8];
            }
#pragma unroll
            for (int mi = 0; mi < 4; mi++)
#pragma unroll
                for (int ni = 0; ni < 4; ni++)
                    acc[mi][ni] = __builtin_amdgcn_mfma_f32_16x16x32_bf16(
                        af[mi], bfr[ni], acc[mi][ni], 0, 0, 0);
        }
    }

    // epilogue: dense stores into a single [M][N] buffer (L2 merges to full lines)
#pragma unroll
    for (int mi = 0; mi < 4; mi++) {
#pragma unroll
        for (int ni = 0; ni < 4; ni++) {
            int col = bn + wn + ni * 16 + r16;
            float bv = bias[col];
#pragma unroll
            for (int rg = 0; rg < 4; rg++) {
                int row = bm + wm + mi * 16 + quad * 4 + rg;
                float val = acc[mi][ni][rg] + bv;
                if (mode == 0) outb[(size_t)row * N + col] = (__bf16)val;
                else           outf[(size_t)row * N + col] = val;
            }
        }
    }
}

// ---------------- flash attention ----------------
// qkv layout: [b*T + t][3C], head h: Q at col h*64, K at 1024+h*64, V at 2048+h*64
// block: 64 q-rows, 4 waves x 16 rows; k-tiles of 64; heavy blocks first.
__global__ __launch_bounds__(256) void attn_kernel(
    const __bf16* __restrict__ qkv, __bf16* __restrict__ y1)
{
    __shared__ __bf16 Ks[64 * 64];       // unpadded (global_load_lds)
    __shared__ __bf16 Vt[64][72];        // V^T, padded
    __shared__ __bf16 Ps[4][16][72];     // per-wave P round-trip

    int tid = threadIdx.x;
    int lane = tid & 63, w = tid >> 6;
    int quad = lane >> 4, r16 = lane & 15;
    int bh = blockIdx.y;
    int b = bh >> 4, h = bh & 15;
    int qb = (gridDim.x - 1 - blockIdx.x) * 64;  // heavy tiles dispatched first

    const __bf16* base = qkv + (size_t)b * T_SEQ * NQKV + h * HD;
    const __bf16* Qh = base;
    const __bf16* Kh = base + CDIM;
    const __bf16* Vh = base + 2 * CDIM;

    const float NEG_INF = -__builtin_inff();
    const float sc2 = 0.125f * 1.44269504088896f;  // 1/sqrt(64) * log2(e)

    // Q fragments (A-operand), loaded once: rows qb + w*16 + r16
    bf16x8 qf[2];
#pragma unroll
    for (int ks = 0; ks < 2; ks++)
        qf[ks] = *(const bf16x8*)(Qh + (size_t)(qb + w * 16 + r16) * NQKV + ks * 32 + quad * 8);

    f32x4 o[4] = {};
    float m_i[4], l_i[4];
#pragma unroll
    for (int rg = 0; rg < 4; rg++) { m_i[rg] = NEG_INF; l_i[rg] = 0.f; }

    int lrow = lane >> 3, lcol8 = (lane & 7) * 8;
    char* lK = (char*)Ks + w * 2048;
    int srow = tid >> 2, sseg = tid & 3;

    int nkt = qb / 64 + 1;
    for (int kt = 0; kt < nkt; kt++) {
        int kb = kt * 64;
        // V prefetch to regs (before barrier)
        const __bf16* vp = Vh + (size_t)(kb + srow) * NQKV + sseg * 16;
        bf16x8 vv0 = *(const bf16x8*)vp;
        bf16x8 vv1 = *(const bf16x8*)(vp + 8);
        __syncthreads();  // prior tile's LDS reads done
        // K: async global->LDS, wave w covers k-rows [w*16, w*16+16)
        const __bf16* kg = Kh + (size_t)(kb + w * 16 + lrow) * NQKV + lcol8;
        async_load16(kg, lK);
        async_load16(kg + (size_t)8 * NQKV, lK + 1024);
        // V: transpose into Vt
#pragma unroll
        for (int j = 0; j < 8; j++) {
            Vt[sseg * 16 + j][srow] = vv0[j];
            Vt[sseg * 16 + 8 + j][srow] = vv1[j];
        }
        __syncthreads();  // drains vmcnt+lgkm

        // S = Q K^T
        f32x4 s[4] = {};
#pragma unroll
        for (int ks = 0; ks < 2; ks++) {
            bf16x8 kf[4];
#pragma unroll
            for (int ni = 0; ni < 4; ni++)
                kf[ni] = *(const bf16x8*)&Ks[(ni * 16 + r16) * 64 + ks * 32 + quad * 8];
#pragma unroll
            for (int ni = 0; ni < 4; ni++)
                s[ni] = __builtin_amdgcn_mfma_f32_16x16x32_bf16(qf[ks], kf[ni], s[ni], 0, 0, 0);
        }
        // scale (exp2 domain) + causal mask (diagonal tile only)
        bool diag = (kb == qb);
#pragma unroll
        for (int ni = 0; ni < 4; ni++)
#pragma unroll
            for (int rg = 0; rg < 4; rg++) {
                float v = s[ni][rg] * sc2;
                if (diag) {
                    int rrow = w * 16 + quad * 4 + rg;
                    int ccol = ni * 16 + r16;
                    if (ccol > rrow) v = NEG_INF;
                }
                s[ni][rg] = v;
            }
        // online softmax (base-2) per row
#pragma unroll
        for (int rg = 0; rg < 4; rg++) {
            float mx = fmaxf(fmaxf(s[0][rg], s[1][rg]), fmaxf(s[2][rg], s[3][rg]));
#pragma unroll
            for (int off = 1; off < 16; off <<= 1)
                mx = fmaxf(mx, __shfl_xor(mx, off, 64));
            float mnew = fmaxf(m_i[rg], mx);
            float alpha = exp2f(m_i[rg] - mnew);
            float rs = 0.f;
#pragma unroll
            for (int ni = 0; ni < 4; ni++) {
                float p = exp2f(s[ni][rg] - mnew);
                s[ni][rg] = p;
                rs += p;
            }
#pragma unroll
            for (int off = 1; off < 16; off <<= 1)
                rs += __shfl_xor(rs, off, 64);
            l_i[rg] = l_i[rg] * alpha + rs;
            m_i[rg] = mnew;
#pragma unroll
            for (int nd = 0; nd < 4; nd++) o[nd][rg] *= alpha;
        }
        // P -> LDS (per-wave region)
#pragma unroll
        for (int ni = 0; ni < 4; ni++)
#pragma unroll
            for (int rg = 0; rg < 4; rg++)
                Ps[w][quad * 4 + rg][ni * 16 + r16] = (__bf16)s[ni][rg];
        // PV
#pragma unroll
        for (int ks = 0; ks < 2; ks++) {
            bf16x8 pf, vf[4];
            pf = *(const bf16x8*)&Ps[w][r16][ks * 32 + quad * 8];
#pragma unroll
            for (int nd = 0; nd < 4; nd++)
                vf[nd] = *(const bf16x8*)&Vt[nd * 16 + r16][ks * 32 + quad * 8];
#pragma unroll
            for (int nd = 0; nd < 4; nd++)
                o[nd] = __builtin_amdgcn_mfma_f32_16x16x32_bf16(pf, vf[nd], o[nd], 0, 0, 0);
        }
    }

    // epilogue: y1[b*T+t][h*64+d] = o / l
#pragma unroll
    for (int rg = 0; rg < 4; rg++) {
        float inv = 1.f / l_i[rg];
        int t = qb + w * 16 + quad * 4 + rg;
#pragma unroll
        for (int nd = 0; nd < 4; nd++) {
            float val = o[nd][rg] * inv;
            y1[(size_t)(b * T_SEQ + t) * CDIM + h * HD + nd * 16 + r16] = (__bf16)val;
        }
    }
}

extern "C" void kernel_launch(void* const* d_in, const int* in_sizes, int n_in,
                              void* d_out, int out_size, void* d_ws, size_t ws_size,
                              hipStream_t stream) {
    const float* x = (const float*)d_in[0];
    const float* W_attn = (const float*)d_in[1];
    const float* b_attn = (const float*)d_in[2];
    const float* W_proj = (const float*)d_in[3];
    const float* b_proj = (const float*)d_in[4];
    float* out = (float*)d_out;

    char* p = (char*)d_ws;
    __bf16* xb = (__bf16*)p;   p += (size_t)MTOT * CDIM * 2;       // 8 MiB (reused as y1)
    __bf16* WaT = (__bf16*)p;  p += (size_t)3 * CDIM * CDIM * 2;   // 6 MiB
    __bf16* WpT = (__bf16*)p;  p += (size_t)CDIM * CDIM * 2;       // 2 MiB
    __bf16* qkv = (__bf16*)p;  p += (size_t)MTOT * NQKV * 2;       // 24 MiB
    __bf16* y1 = xb;  // x no longer needed after QKV GEMM

    cvt_bf16_kernel<<<2048, 256, 0, stream>>>(x, xb, MTOT * CDIM);
    transpose_bf16_kernel<<<dim3(96, 32), dim3(32, 8), 0, stream>>>(W_attn, WaT, CDIM, 3 * CDIM);
    transpose_bf16_kernel<<<dim3(32, 32), dim3(32, 8), 0, stream>>>(W_proj, WpT, CDIM, CDIM);
    gemm_bt_kernel<<<dim3(24, 32), 256, 0, stream>>>(xb, WaT, b_attn, MTOT, NQKV, CDIM, 0,
                                                     qkv, nullptr);
    attn_kernel<<<dim3(32, 32), 256, 0, stream>>>(qkv, y1);
    gemm_bt_kernel<<<dim3(8, 32), 256, 0, stream>>>(y1, WpT, b_proj, MTOT, CDIM, CDIM, 1,
                                                    nullptr, out);
}

// Round 3
// 269.410 us; speedup vs baseline: 1.4653x; 1.1851x over previous
//
#include <hip/hip_runtime.h>

typedef __attribute__((ext_vector_type(8))) __bf16 bf16x8;
typedef __attribute__((ext_vector_type(4))) float f32x4;

#define T_SEQ 2048
#define NH 16
#define HD 64
#define CDIM 1024
#define NQK 2048   // Q|K buffer row stride
#define NQKV 3072
#define MTOT 4096  // B*T

__device__ __forceinline__ void async_load16(const void* g, void* l) {
    __builtin_amdgcn_global_load_lds(
        (const __attribute__((address_space(1))) void*)g,
        (__attribute__((address_space(3))) void*)l, 16, 0, 0);
}

// ---------------- convert fp32 -> bf16 ----------------
__global__ __launch_bounds__(256) void cvt_bf16_kernel(const float* __restrict__ in,
                                                       __bf16* __restrict__ out, int n) {
    int i = (blockIdx.x * 256 + threadIdx.x) * 8;
    if (i + 8 <= n) {
        float4 f0 = *(const float4*)(in + i);
        float4 f1 = *(const float4*)(in + i + 4);
        bf16x8 o;
        o[0] = (__bf16)f0.x; o[1] = (__bf16)f0.y; o[2] = (__bf16)f0.z; o[3] = (__bf16)f0.w;
        o[4] = (__bf16)f1.x; o[5] = (__bf16)f1.y; o[6] = (__bf16)f1.z; o[7] = (__bf16)f1.w;
        *(bf16x8*)(out + i) = o;
    }
}

// ---------------- transpose fp32 [R][C] -> bf16 [C][R] ----------------
__global__ __launch_bounds__(256) void transpose_bf16_kernel(const float* __restrict__ in,
                                                             __bf16* __restrict__ out,
                                                             int R, int C) {
    __shared__ float tile[32][33];
    int c0 = blockIdx.x * 32, r0 = blockIdx.y * 32;
    int tx = threadIdx.x, ty = threadIdx.y;
#pragma unroll
    for (int i = 0; i < 4; i++)
        tile[ty + i * 8][tx] = in[(size_t)(r0 + ty + i * 8) * C + c0 + tx];
    __syncthreads();
#pragma unroll
    for (int i = 0; i < 4; i++)
        out[(size_t)(c0 + ty + i * 8) * R + r0 + tx] = (__bf16)tile[tx][ty + i * 8];
}

// ---------------- GEMM: C[m][n] = sum_k A[m][k]*Bt[n][k] + bias[n] ----------------
// mode 0 (QKV): cols [0,2048) -> qkb [M][2048] bf16 (Q cols pre-scaled by 1/8*log2e);
//               cols [2048,3072) -> V^T vtb [2][1024][2048] bf16 (packed 8B stores)
// mode 1: fp32 store to outf [M][N]
__global__ __launch_bounds__(256) void gemm_bt_kernel(
    const __bf16* __restrict__ A, const __bf16* __restrict__ Bt,
    const float* __restrict__ bias, int M, int N, int K, int mode,
    __bf16* __restrict__ qkb, __bf16* __restrict__ vtb, float* __restrict__ outf)
{
    __shared__ __bf16 As[128 * 64];   // unpadded: global_load_lds layout
    __shared__ __bf16 Bs[128 * 64];

    int tid = threadIdx.x;
    int lane = tid & 63, wid = tid >> 6;
    int quad = lane >> 4, r16 = lane & 15;
    int wm = (wid >> 1) * 64, wn = (wid & 1) * 64;
    int bm = blockIdx.y * 128, bn = blockIdx.x * 128;

    f32x4 acc[4][4] = {};

    int lrow = lane >> 3;          // 0..7
    int lcol = (lane & 7) * 8;     // element col within 64
    const __bf16* Ag = A + (size_t)(bm + wid * 32 + lrow) * K + lcol;
    const __bf16* Bg = Bt + (size_t)(bn + wid * 32 + lrow) * K + lcol;
    char* lA = (char*)As + wid * 4096;
    char* lB = (char*)Bs + wid * 4096;

    for (int kt = 0; kt < K; kt += 64) {
        __syncthreads();
#pragma unroll
        for (int i = 0; i < 4; i++) {
            async_load16(Ag + kt + (size_t)i * 8 * K, lA + i * 1024);
            async_load16(Bg + kt + (size_t)i * 8 * K, lB + i * 1024);
        }
        __syncthreads();
#pragma unroll
        for (int ks = 0; ks < 2; ks++) {
            bf16x8 af[4], bfr[4];
#pragma unroll
            for (int i = 0; i < 4; i++) {
                af[i] = *(const bf16x8*)&As[(wm + i * 16 + r16) * 64 + ks * 32 + quad * 8];
                bfr[i] = *(const bf16x8*)&Bs[(wn + i * 16 + r16) * 64 + ks * 32 + quad * 8];
            }
#pragma unroll
            for (int mi = 0; mi < 4; mi++)
#pragma unroll
                for (int ni = 0; ni < 4; ni++)
                    acc[mi][ni] = __builtin_amdgcn_mfma_f32_16x16x32_bf16(
                        af[mi], bfr[ni], acc[mi][ni], 0, 0, 0);
        }
    }

    const float SC2 = 0.125f * 1.44269504088896f;  // 1/sqrt(64) * log2(e)
#pragma unroll
    for (int mi = 0; mi < 4; mi++) {
#pragma unroll
        for (int ni = 0; ni < 4; ni++) {
            int col = bn + wn + ni * 16 + r16;
            float bv = bias[col];
            int row0 = bm + wm + mi * 16 + quad * 4;
            if (mode == 1) {
#pragma unroll
                for (int rg = 0; rg < 4; rg++)
                    outf[(size_t)(row0 + rg) * N + col] = acc[mi][ni][rg] + bv;
            } else if (col < 1024) {  // Q, pre-scaled
#pragma unroll
                for (int rg = 0; rg < 4; rg++)
                    qkb[(size_t)(row0 + rg) * NQK + col] = (__bf16)((acc[mi][ni][rg] + bv) * SC2);
            } else if (col < 2048) {  // K
#pragma unroll
                for (int rg = 0; rg < 4; rg++)
                    qkb[(size_t)(row0 + rg) * NQK + col] = (__bf16)(acc[mi][ni][rg] + bv);
            } else {                  // V -> V^T [b][d][t], 4 consecutive t -> 8B store
                int dcol = col - 2048;
                int b = row0 >> 11, t0 = row0 & 2047;
                union { __bf16 h[4]; uint2 u; } pk;
#pragma unroll
                for (int rg = 0; rg < 4; rg++) pk.h[rg] = (__bf16)(acc[mi][ni][rg] + bv);
                *(uint2*)&vtb[((size_t)b * 1024 + dcol) * T_SEQ + t0] = pk.u;
            }
        }
    }
}

// ---------------- flash attention, S^T formulation ----------------
// qkb: [b*T+t][2048] (Q cols h*64.., K cols 1024+h*64..); vtb: [b][1024 d][2048 t]
// block: 64 q-rows, 4 waves x 16 rows; each lane owns one q-row's scores (16/tile).
__global__ __launch_bounds__(256) void attn_kernel(
    const __bf16* __restrict__ qkb, const __bf16* __restrict__ vtb,
    __bf16* __restrict__ y1)
{
    __shared__ __bf16 Ks[64 * 64];   // K tile  [kv][d]   unpadded (async)
    __shared__ __bf16 Vs[64 * 64];   // V^T tile [d][t]   unpadded (async)
    __shared__ __bf16 Ps[4][16][72]; // per-wave P round-trip [q][kv]

    int tid = threadIdx.x;
    int lane = tid & 63, w = tid >> 6;
    int quad = lane >> 4, r16 = lane & 15;
    int bh = blockIdx.y;
    int b = bh >> 4, h = bh & 15;
    int qb = ((int)gridDim.x - 1 - (int)blockIdx.x) * 64;  // heavy tiles first

    const __bf16* Qh = qkb + (size_t)b * T_SEQ * NQK + h * HD;
    const __bf16* Kh = Qh + CDIM;
    const __bf16* Vh = vtb + ((size_t)b * 1024 + h * HD) * T_SEQ;

    const float NEG_INF = -__builtin_inff();

    // Q fragments (B-operand: n = q-row = r16, k = dim)
    bf16x8 qf[2];
#pragma unroll
    for (int ks = 0; ks < 2; ks++)
        qf[ks] = *(const bf16x8*)(Qh + (size_t)(qb + w * 16 + r16) * NQK + ks * 32 + quad * 8);

    f32x4 o[4] = {};
    float m_i = NEG_INF, l_i = 0.f;

    int lrow = lane >> 3, lcol8 = (lane & 7) * 8;
    char* lK = (char*)Ks + w * 2048;
    char* lV = (char*)Vs + w * 2048;
    int qrow = qb + w * 16 + r16;

    int nkt = qb / 64 + 1;
    for (int kt = 0; kt < nkt; kt++) {
        int kb = kt * 64;
        __syncthreads();  // prior tile's LDS reads done
        const __bf16* kg = Kh + (size_t)(kb + w * 16 + lrow) * NQK + lcol8;
        const __bf16* vg = Vh + (size_t)(w * 16 + lrow) * T_SEQ + kb + lcol8;
        async_load16(kg, lK);
        async_load16(kg + (size_t)8 * NQK, lK + 1024);
        async_load16(vg, lV);
        async_load16(vg + (size_t)8 * T_SEQ, lV + 1024);
        __syncthreads();  // drains vmcnt

        // S^T = K * Q^T: s[ni][rg] = S[kv = kb+ni*16+quad*4+rg][q = qrow]
        f32x4 s[4] = {};
#pragma unroll
        for (int ks = 0; ks < 2; ks++) {
            bf16x8 kf[4];
#pragma unroll
            for (int ni = 0; ni < 4; ni++)
                kf[ni] = *(const bf16x8*)&Ks[(ni * 16 + r16) * 64 + ks * 32 + quad * 8];
#pragma unroll
            for (int ni = 0; ni < 4; ni++)
                s[ni] = __builtin_amdgcn_mfma_f32_16x16x32_bf16(kf[ni], qf[ks], s[ni], 0, 0, 0);
        }
        if (kb == qb) {  // diagonal: causal mask
#pragma unroll
            for (int ni = 0; ni < 4; ni++)
#pragma unroll
                for (int rg = 0; rg < 4; rg++)
                    if (kb + ni * 16 + quad * 4 + rg > qrow) s[ni][rg] = NEG_INF;
        }
        // row reduce: 16 in-lane values, then across the 4 quads
        float mx = NEG_INF;
#pragma unroll
        for (int ni = 0; ni < 4; ni++)
#pragma unroll
            for (int rg = 0; rg < 4; rg++) mx = fmaxf(mx, s[ni][rg]);
        mx = fmaxf(mx, __shfl_xor(mx, 16, 64));
        mx = fmaxf(mx, __shfl_xor(mx, 32, 64));
        float mnew = fmaxf(m_i, mx);
        float alpha = exp2f(m_i - mnew);
        float rs = 0.f;
#pragma unroll
        for (int ni = 0; ni < 4; ni++)
#pragma unroll
            for (int rg = 0; rg < 4; rg++) {
                float p = exp2f(s[ni][rg] - mnew);
                s[ni][rg] = p;
                rs += p;
            }
        rs += __shfl_xor(rs, 16, 64);
        rs += __shfl_xor(rs, 32, 64);
        l_i = l_i * alpha + rs;
        m_i = mnew;
        // broadcast alpha from lane (q-row) to O layout rows (quad*4+rg)
        int ai = __float_as_int(alpha);
        float ar[4];
#pragma unroll
        for (int rg = 0; rg < 4; rg++)
            ar[rg] = __int_as_float(__builtin_amdgcn_ds_bpermute((quad * 4 + rg) * 4, ai));
#pragma unroll
        for (int nd = 0; nd < 4; nd++)
#pragma unroll
            for (int rg = 0; rg < 4; rg++) o[nd][rg] *= ar[rg];
        // P -> LDS [q][kv], packed 8B (4 consecutive kv)
#pragma unroll
        for (int ni = 0; ni < 4; ni++) {
            union { __bf16 h[4]; uint2 u; } pk;
#pragma unroll
            for (int rg = 0; rg < 4; rg++) pk.h[rg] = (__bf16)s[ni][rg];
            *(uint2*)&Ps[w][r16][ni * 16 + quad * 4] = pk.u;
        }
        // PV: A = P (m=q, k=kv), B = V^T (n=d, k=kv)
#pragma unroll
        for (int ks = 0; ks < 2; ks++) {
            bf16x8 pf = *(const bf16x8*)&Ps[w][r16][ks * 32 + quad * 8];
            bf16x8 vf[4];
#pragma unroll
            for (int nd = 0; nd < 4; nd++)
                vf[nd] = *(const bf16x8*)&Vs[(nd * 16 + r16) * 64 + ks * 32 + quad * 8];
#pragma unroll
            for (int nd = 0; nd < 4; nd++)
                o[nd] = __builtin_amdgcn_mfma_f32_16x16x32_bf16(pf, vf[nd], o[nd], 0, 0, 0);
        }
    }

    // epilogue: o row = quad*4+rg (q), col = d = nd*16+r16; scale by 1/l of that row
    float inv = 1.f / l_i;
    int ii = __float_as_int(inv);
#pragma unroll
    for (int rg = 0; rg < 4; rg++) {
        float ir = __int_as_float(__builtin_amdgcn_ds_bpermute((quad * 4 + rg) * 4, ii));
        int t = qb + w * 16 + quad * 4 + rg;
#pragma unroll
        for (int nd = 0; nd < 4; nd++)
            y1[(size_t)(b * T_SEQ + t) * CDIM + h * HD + nd * 16 + r16] =
                (__bf16)(o[nd][rg] * ir);
    }
}

extern "C" void kernel_launch(void* const* d_in, const int* in_sizes, int n_in,
                              void* d_out, int out_size, void* d_ws, size_t ws_size,
                              hipStream_t stream) {
    const float* x = (const float*)d_in[0];
    const float* W_attn = (const float*)d_in[1];
    const float* b_attn = (const float*)d_in[2];
    const float* W_proj = (const float*)d_in[3];
    const float* b_proj = (const float*)d_in[4];
    float* out = (float*)d_out;

    char* p = (char*)d_ws;
    __bf16* xb = (__bf16*)p;   p += (size_t)MTOT * CDIM * 2;       // 8 MiB (reused as y1)
    __bf16* WaT = (__bf16*)p;  p += (size_t)3 * CDIM * CDIM * 2;   // 6 MiB
    __bf16* WpT = (__bf16*)p;  p += (size_t)CDIM * CDIM * 2;       // 2 MiB
    __bf16* qkb = (__bf16*)p;  p += (size_t)MTOT * NQK * 2;        // 16 MiB
    __bf16* vtb = (__bf16*)p;  p += (size_t)2 * 1024 * T_SEQ * 2;  // 8 MiB
    __bf16* y1 = xb;  // x no longer needed after QKV GEMM

    cvt_bf16_kernel<<<2048, 256, 0, stream>>>(x, xb, MTOT * CDIM);
    transpose_bf16_kernel<<<dim3(96, 32), dim3(32, 8), 0, stream>>>(W_attn, WaT, CDIM, 3 * CDIM);
    transpose_bf16_kernel<<<dim3(32, 32), dim3(32, 8), 0, stream>>>(W_proj, WpT, CDIM, CDIM);
    gemm_bt_kernel<<<dim3(24, 32), 256, 0, stream>>>(xb, WaT, b_attn, MTOT, NQKV, CDIM, 0,
                                                     qkb, vtb, nullptr);
    attn_kernel<<<dim3(32, 32), 256, 0, stream>>>(qkb, vtb, y1);
    gemm_bt_kernel<<<dim3(8, 32), 256, 0, stream>>>(y1, WpT, b_proj, MTOT, CDIM, CDIM, 1,
                                                    nullptr, nullptr, out);
}

// Round 5
// 233.091 us; speedup vs baseline: 1.6936x; 1.1558x over previous
//
#include <hip/hip_runtime.h>

typedef __attribute__((ext_vector_type(8))) __bf16 bf16x8;
typedef __attribute__((ext_vector_type(4))) float f32x4;

#define T_SEQ 2048
#define NH 16
#define HD 64
#define CDIM 1024
#define NQK 2048   // Q|K buffer row stride
#define NQKV 3072
#define MTOT 4096  // B*T

// XOR-swizzled LDS layout: global 16B-chunk c of row r lives at slot (c ^ (r&7)).
// SWZ returns the ELEMENT offset of that chunk.
#define SWZ(r, c) ((((r) * 8) + ((c) ^ ((r) & 7))) * 8)

__device__ __forceinline__ void async_load16(const void* g, void* l) {
    __builtin_amdgcn_global_load_lds(
        (const __attribute__((address_space(1))) void*)g,
        (__attribute__((address_space(3))) void*)l, 16, 0, 0);
}

// ---------------- convert fp32 -> bf16 ----------------
__global__ __launch_bounds__(256) void cvt_bf16_kernel(const float* __restrict__ in,
                                                       __bf16* __restrict__ out, int n) {
    int i = (blockIdx.x * 256 + threadIdx.x) * 8;
    if (i + 8 <= n) {
        float4 f0 = *(const float4*)(in + i);
        float4 f1 = *(const float4*)(in + i + 4);
        bf16x8 o;
        o[0] = (__bf16)f0.x; o[1] = (__bf16)f0.y; o[2] = (__bf16)f0.z; o[3] = (__bf16)f0.w;
        o[4] = (__bf16)f1.x; o[5] = (__bf16)f1.y; o[6] = (__bf16)f1.z; o[7] = (__bf16)f1.w;
        *(bf16x8*)(out + i) = o;
    }
}

// ---------------- transpose fp32 [R][C] -> bf16 [C][R] ----------------
__global__ __launch_bounds__(256) void transpose_bf16_kernel(const float* __restrict__ in,
                                                             __bf16* __restrict__ out,
                                                             int R, int C) {
    __shared__ float tile[32][33];
    int c0 = blockIdx.x * 32, r0 = blockIdx.y * 32;
    int tx = threadIdx.x, ty = threadIdx.y;
#pragma unroll
    for (int i = 0; i < 4; i++)
        tile[ty + i * 8][tx] = in[(size_t)(r0 + ty + i * 8) * C + c0 + tx];
    __syncthreads();
#pragma unroll
    for (int i = 0; i < 4; i++)
        out[(size_t)(c0 + ty + i * 8) * R + r0 + tx] = (__bf16)tile[tx][ty + i * 8];
}

// ---------------- GEMM: C[m][n] = sum_k A[m][k]*Bt[n][k] + bias[n] ----------------
// mode 0 (QKV): cols [0,2048) -> qkb [M][2048] bf16 (Q cols pre-scaled by 1/8*log2e);
//               cols [2048,3072) -> V^T vtb [2][1024][2048] bf16 (packed 8B stores)
// mode 1: fp32 store to outf [M][N]
__global__ __launch_bounds__(256) void gemm_bt_kernel(
    const __bf16* __restrict__ A, const __bf16* __restrict__ Bt,
    const float* __restrict__ bias, int M, int N, int K, int mode,
    __bf16* __restrict__ qkb, __bf16* __restrict__ vtb, float* __restrict__ outf)
{
    __shared__ __bf16 As[128 * 64];   // unpadded, XOR-swizzled
    __shared__ __bf16 Bs[128 * 64];

    int tid = threadIdx.x;
    int lane = tid & 63, wid = tid >> 6;
    int quad = lane >> 4, r16 = lane & 15;
    int wm = (wid >> 1) * 64, wn = (wid & 1) * 64;
    int bm = blockIdx.y * 128, bn = blockIdx.x * 128;

    f32x4 acc[4][4] = {};

    int lrow = lane >> 3;                              // 0..7
    int lcolsw = (((lane & 7) ^ (lrow & 7)) * 8);      // swizzled source col
    const __bf16* Ag = A + (size_t)(bm + wid * 32 + lrow) * K + lcolsw;
    const __bf16* Bg = Bt + (size_t)(bn + wid * 32 + lrow) * K + lcolsw;
    char* lA = (char*)As + wid * 4096;
    char* lB = (char*)Bs + wid * 4096;

    for (int kt = 0; kt < K; kt += 64) {
        __syncthreads();
#pragma unroll
        for (int i = 0; i < 4; i++) {
            async_load16(Ag + kt + (size_t)i * 8 * K, lA + i * 1024);
            async_load16(Bg + kt + (size_t)i * 8 * K, lB + i * 1024);
        }
        __syncthreads();
#pragma unroll
        for (int ks = 0; ks < 2; ks++) {
            bf16x8 af[4], bfr[4];
#pragma unroll
            for (int i = 0; i < 4; i++) {
                af[i] = *(const bf16x8*)&As[SWZ(wm + i * 16 + r16, ks * 4 + quad)];
                bfr[i] = *(const bf16x8*)&Bs[SWZ(wn + i * 16 + r16, ks * 4 + quad)];
            }
#pragma unroll
            for (int mi = 0; mi < 4; mi++)
#pragma unroll
                for (int ni = 0; ni < 4; ni++)
                    acc[mi][ni] = __builtin_amdgcn_mfma_f32_16x16x32_bf16(
                        af[mi], bfr[ni], acc[mi][ni], 0, 0, 0);
        }
    }

    const float SC2 = 0.125f * 1.44269504088896f;  // 1/sqrt(64) * log2(e)
#pragma unroll
    for (int mi = 0; mi < 4; mi++) {
#pragma unroll
        for (int ni = 0; ni < 4; ni++) {
            int col = bn + wn + ni * 16 + r16;
            float bv = bias[col];
            int row0 = bm + wm + mi * 16 + quad * 4;
            if (mode == 1) {
#pragma unroll
                for (int rg = 0; rg < 4; rg++)
                    outf[(size_t)(row0 + rg) * N + col] = acc[mi][ni][rg] + bv;
            } else if (col < 1024) {  // Q, pre-scaled
#pragma unroll
                for (int rg = 0; rg < 4; rg++)
                    qkb[(size_t)(row0 + rg) * NQK + col] = (__bf16)((acc[mi][ni][rg] + bv) * SC2);
            } else if (col < 2048) {  // K
#pragma unroll
                for (int rg = 0; rg < 4; rg++)
                    qkb[(size_t)(row0 + rg) * NQK + col] = (__bf16)(acc[mi][ni][rg] + bv);
            } else {                  // V -> V^T [b][d][t], 4 consecutive t -> 8B store
                int dcol = col - 2048;
                int b = row0 >> 11, t0 = row0 & 2047;
                union { __bf16 h[4]; uint2 u; } pk;
#pragma unroll
                for (int rg = 0; rg < 4; rg++) pk.h[rg] = (__bf16)(acc[mi][ni][rg] + bv);
                *(uint2*)&vtb[((size_t)b * 1024 + dcol) * T_SEQ + t0] = pk.u;
            }
        }
    }
}

// ---------------- flash attention, S^T formulation ----------------
// qkb: [b*T+t][2048] (Q cols h*64.., K cols 1024+h*64..); vtb: [b][1024 d][2048 t]
// block: 64 q-rows, 4 waves x 16 rows; each lane owns one q-row's scores (16/tile).
__global__ __launch_bounds__(256) void attn_kernel(
    const __bf16* __restrict__ qkb, const __bf16* __restrict__ vtb,
    __bf16* __restrict__ y1)
{
    __shared__ __bf16 Ks[64 * 64];   // K tile  [kv][d]   unpadded, swizzled
    __shared__ __bf16 Vs[64 * 64];   // V^T tile [d][t]   unpadded, swizzled
    __shared__ __bf16 Ps[4][16][72]; // per-wave P round-trip [q][kv]

    int tid = threadIdx.x;
    int lane = tid & 63, w = tid >> 6;
    int quad = lane >> 4, r16 = lane & 15;
    int bh = blockIdx.y;
    int b = bh >> 4, h = bh & 15;
    int qb = ((int)gridDim.x - 1 - (int)blockIdx.x) * 64;  // heavy tiles first

    const __bf16* Qh = qkb + (size_t)b * T_SEQ * NQK + h * HD;
    const __bf16* Kh = Qh + CDIM;
    const __bf16* Vh = vtb + ((size_t)b * 1024 + h * HD) * T_SEQ;

    const float NEG_INF = -__builtin_inff();

    // Q fragments (B-operand: n = q-row = r16, k = dim)
    bf16x8 qf[2];
#pragma unroll
    for (int ks = 0; ks < 2; ks++)
        qf[ks] = *(const bf16x8*)(Qh + (size_t)(qb + w * 16 + r16) * NQK + ks * 32 + quad * 8);

    f32x4 o[4] = {};
    float m_i = NEG_INF, l_i = 0.f;

    int lrow = lane >> 3;
    int lcolsw = (((lane & 7) ^ (lrow & 7)) * 8);   // swizzled source col
    char* lK = (char*)Ks + w * 2048;
    char* lV = (char*)Vs + w * 2048;
    int qrow = qb + w * 16 + r16;

    int nkt = qb / 64 + 1;
    for (int kt = 0; kt < nkt; kt++) {
        int kb = kt * 64;
        __syncthreads();  // prior tile's LDS reads done
        const __bf16* kg = Kh + (size_t)(kb + w * 16 + lrow) * NQK + lcolsw;
        const __bf16* vg = Vh + (size_t)(w * 16 + lrow) * T_SEQ + kb + lcolsw;
        async_load16(kg, lK);
        async_load16(kg + (size_t)8 * NQK, lK + 1024);
        async_load16(vg, lV);
        async_load16(vg + (size_t)8 * T_SEQ, lV + 1024);
        __syncthreads();  // drains vmcnt

        // S^T = K * Q^T: s[ni][rg] = S[kv = kb+ni*16+quad*4+rg][q = qrow]
        f32x4 s[4] = {};
#pragma unroll
        for (int ks = 0; ks < 2; ks++) {
            bf16x8 kf[4];
#pragma unroll
            for (int ni = 0; ni < 4; ni++)
                kf[ni] = *(const bf16x8*)&Ks[SWZ(ni * 16 + r16, ks * 4 + quad)];
#pragma unroll
            for (int ni = 0; ni < 4; ni++)
                s[ni] = __builtin_amdgcn_mfma_f32_16x16x32_bf16(kf[ni], qf[ks], s[ni], 0, 0, 0);
        }
        if (kb == qb) {  // diagonal: causal mask
#pragma unroll
            for (int ni = 0; ni < 4; ni++)
#pragma unroll
                for (int rg = 0; rg < 4; rg++)
                    if (kb + ni * 16 + quad * 4 + rg > qrow) s[ni][rg] = NEG_INF;
        }
        // row reduce: 16 in-lane values, then across the 4 quads
        float mx = NEG_INF;
#pragma unroll
        for (int ni = 0; ni < 4; ni++)
#pragma unroll
            for (int rg = 0; rg < 4; rg++) mx = fmaxf(mx, s[ni][rg]);
        mx = fmaxf(mx, __shfl_xor(mx, 16, 64));
        mx = fmaxf(mx, __shfl_xor(mx, 32, 64));
        float mnew = fmaxf(m_i, mx);
        float alpha = exp2f(m_i - mnew);
        float rs = 0.f;
#pragma unroll
        for (int ni = 0; ni < 4; ni++)
#pragma unroll
            for (int rg = 0; rg < 4; rg++) {
                float p = exp2f(s[ni][rg] - mnew);
                s[ni][rg] = p;
                rs += p;
            }
        rs += __shfl_xor(rs, 16, 64);
        rs += __shfl_xor(rs, 32, 64);
        l_i = l_i * alpha + rs;
        m_i = mnew;
        // broadcast alpha from lane (q-row) to O layout rows (quad*4+rg)
        int ai = __float_as_int(alpha);
        float ar[4];
#pragma unroll
        for (int rg = 0; rg < 4; rg++)
            ar[rg] = __int_as_float(__builtin_amdgcn_ds_bpermute((quad * 4 + rg) * 4, ai));
#pragma unroll
        for (int nd = 0; nd < 4; nd++)
#pragma unroll
            for (int rg = 0; rg < 4; rg++) o[nd][rg] *= ar[rg];
        // P -> LDS [q][kv], packed 8B (4 consecutive kv)
#pragma unroll
        for (int ni = 0; ni < 4; ni++) {
            union { __bf16 h[4]; uint2 u; } pk;
#pragma unroll
            for (int rg = 0; rg < 4; rg++) pk.h[rg] = (__bf16)s[ni][rg];
            *(uint2*)&Ps[w][r16][ni * 16 + quad * 4] = pk.u;
        }
        // PV: A = P (m=q, k=kv), B = V^T (n=d, k=kv)
#pragma unroll
        for (int ks = 0; ks < 2; ks++) {
            bf16x8 pf = *(const bf16x8*)&Ps[w][r16][ks * 32 + quad * 8];
            bf16x8 vf[4];
#pragma unroll
            for (int nd = 0; nd < 4; nd++)
                vf[nd] = *(const bf16x8*)&Vs[SWZ(nd * 16 + r16, ks * 4 + quad)];
#pragma unroll
            for (int nd = 0; nd < 4; nd++)
                o[nd] = __builtin_amdgcn_mfma_f32_16x16x32_bf16(pf, vf[nd], o[nd], 0, 0, 0);
        }
    }

    // epilogue: o row = quad*4+rg (q), col = d = nd*16+r16; scale by 1/l of that row
    float inv = 1.f / l_i;
    int ii = __float_as_int(inv);
#pragma unroll
    for (int rg = 0; rg < 4; rg++) {
        float ir = __int_as_float(__builtin_amdgcn_ds_bpermute((quad * 4 + rg) * 4, ii));
        int t = qb + w * 16 + quad * 4 + rg;
#pragma unroll
        for (int nd = 0; nd < 4; nd++)
            y1[(size_t)(b * T_SEQ + t) * CDIM + h * HD + nd * 16 + r16] =
                (__bf16)(o[nd][rg] * ir);
    }
}

extern "C" void kernel_launch(void* const* d_in, const int* in_sizes, int n_in,
                              void* d_out, int out_size, void* d_ws, size_t ws_size,
                              hipStream_t stream) {
    const float* x = (const float*)d_in[0];
    const float* W_attn = (const float*)d_in[1];
    const float* b_attn = (const float*)d_in[2];
    const float* W_proj = (const float*)d_in[3];
    const float* b_proj = (const float*)d_in[4];
    float* out = (float*)d_out;

    char* p = (char*)d_ws;
    __bf16* xb = (__bf16*)p;   p += (size_t)MTOT * CDIM * 2;       // 8 MiB (reused as y1)
    __bf16* WaT = (__bf16*)p;  p += (size_t)3 * CDIM * CDIM * 2;   // 6 MiB
    __bf16* WpT = (__bf16*)p;  p += (size_t)CDIM * CDIM * 2;       // 2 MiB
    __bf16* qkb = (__bf16*)p;  p += (size_t)MTOT * NQK * 2;        // 16 MiB
    __bf16* vtb = (__bf16*)p;  p += (size_t)2 * 1024 * T_SEQ * 2;  // 8 MiB
    __bf16* y1 = xb;  // x no longer needed after QKV GEMM

    cvt_bf16_kernel<<<2048, 256, 0, stream>>>(x, xb, MTOT * CDIM);
    transpose_bf16_kernel<<<dim3(96, 32), dim3(32, 8), 0, stream>>>(W_attn, WaT, CDIM, 3 * CDIM);
    transpose_bf16_kernel<<<dim3(32, 32), dim3(32, 8), 0, stream>>>(W_proj, WpT, CDIM, CDIM);
    gemm_bt_kernel<<<dim3(24, 32), 256, 0, stream>>>(xb, WaT, b_attn, MTOT, NQKV, CDIM, 0,
                                                     qkb, vtb, nullptr);
    attn_kernel<<<dim3(32, 32), 256, 0, stream>>>(qkb, vtb, y1);
    gemm_bt_kernel<<<dim3(8, 32), 256, 0, stream>>>(y1, WpT, b_proj, MTOT, CDIM, CDIM, 1,
                                                    nullptr, nullptr, out);
}